// Round 7
// baseline (671.823 us; speedup 1.0000x reference)
//
#include <hip/hip_runtime.h>
#include <hip/hip_bf16.h>
#include <stdint.h>

// DTYPE CONTRACT (locked R3): inputs f32, output f32 [loss, probs(128000)].
// WS MAP (223,232,000 B proven):
//   [0, 26.6M)        w_ws fp32 [row][52]; after k_scan: parts @+0, q_bf @+2.0M, wr_bf @+16.0M
//   [26.6M, 157.7M)   ea_ws bf16 INTERLEAVED [row][256][{e,a}] (k_ea -> k_scan)
//   [157.7M, 223.2M)  union: qa_bf + wcomb (k_cvt -> k_ea), then reads_ws (k_scan -> k_final)

#define BATCH 256
#define TLEN  500
#define DKQ   128
#define DVV   256
#define MSZ   50
#define NROWS 128000
#define GSZ   10

__device__ __forceinline__ float bfs(uint16_t u){
  union { uint32_t u; float f; } v; v.u = ((uint32_t)u) << 16; return v.f;
}
__device__ __forceinline__ float bflo32(uint32_t u){
  union { uint32_t u; float f; } v; v.u = u << 16; return v.f;
}
__device__ __forceinline__ float bfhi32(uint32_t u){
  union { uint32_t u; float f; } v; v.u = u & 0xffff0000u; return v.f;
}
__device__ __forceinline__ uint16_t f2b(float x){
  union { __hip_bfloat16 h; uint16_t u; } c; c.h = __float2bfloat16(x); return c.u;
}

typedef __attribute__((ext_vector_type(8))) short bf16x8;
typedef __attribute__((ext_vector_type(4))) float f32x4;

__device__ __forceinline__ void gl_lds16(const void* g, void* l){
  __builtin_amdgcn_global_load_lds(
      (const __attribute__((address_space(1))) void*)g,
      (__attribute__((address_space(3))) void*)l, 16, 0, 0);
}

// =====================================================================
// K1a: w = softmax(q_e @ Mk^T) -> w_ws fp32 [row][52]  (unchanged)
// =====================================================================
__global__ __launch_bounds__(128, 1) void k_w(
    const int* __restrict__ q_data, const float* __restrict__ q_tab,
    const float* __restrict__ Mk, float* __restrict__ w_ws)
{
  __shared__ float mk[MSZ*DKQ];
  __shared__ float wt[128*52];
  const int tid = threadIdx.x;
  for (int li = tid; li < 1600; li += 128)
    ((float4*)mk)[li] = ((const float4*)Mk)[li];
  __syncthreads();

  const int row = blockIdx.x*128 + tid;
  const int qi = q_data[row];
  const float4* qrow = (const float4*)(q_tab + (size_t)qi*DKQ);

  float acc[MSZ];
  #pragma unroll
  for (int m=0;m<MSZ;m++) acc[m] = 0.f;

  #pragma unroll 1
  for (int c8=0; c8<8; c8++){
    float4 q0 = qrow[c8*4+0], q1 = qrow[c8*4+1], q2 = qrow[c8*4+2], q3 = qrow[c8*4+3];
    #pragma unroll
    for (int m=0;m<MSZ;m++){
      const float4* mr = (const float4*)&mk[m*DKQ + c8*16];
      float4 a = mr[0], b = mr[1], cc = mr[2], d = mr[3];
      float s = acc[m];
      s = fmaf(q0.x,a.x,s);  s = fmaf(q0.y,a.y,s);  s = fmaf(q0.z,a.z,s);  s = fmaf(q0.w,a.w,s);
      s = fmaf(q1.x,b.x,s);  s = fmaf(q1.y,b.y,s);  s = fmaf(q1.z,b.z,s);  s = fmaf(q1.w,b.w,s);
      s = fmaf(q2.x,cc.x,s); s = fmaf(q2.y,cc.y,s); s = fmaf(q2.z,cc.z,s); s = fmaf(q2.w,cc.w,s);
      s = fmaf(q3.x,d.x,s);  s = fmaf(q3.y,d.y,s);  s = fmaf(q3.z,d.z,s);  s = fmaf(q3.w,d.w,s);
      acc[m] = s;
    }
  }
  float mx = acc[0];
  #pragma unroll
  for (int m=1;m<MSZ;m++) mx = fmaxf(mx, acc[m]);
  float s = 0.f;
  #pragma unroll
  for (int m=0;m<MSZ;m++){ acc[m] = __expf(acc[m]-mx); s += acc[m]; }
  float inv = 1.0f / s;
  #pragma unroll
  for (int m=0;m<MSZ;m++) wt[tid*52+m] = acc[m]*inv;
  wt[tid*52+50] = 0.f; wt[tid*52+51] = 0.f;   // zero pad -> masking-free k_scan
  __syncthreads();
  float4* dst = (float4*)(w_ws + (size_t)blockIdx.x*128*52);
  const float4* src = (const float4*)wt;
  for (int li = tid; li < 1664; li += 128) dst[li] = src[li];
}

// =====================================================================
// K-cvt: qa_tab f32 -> bf16  AND  Wcomb = [We|Wa] f32 -> bf16
// =====================================================================
__global__ __launch_bounds__(256) void k_cvt(
    const float* __restrict__ qa_tab, const float* __restrict__ We,
    const float* __restrict__ Wa, uint16_t* __restrict__ qa_bf,
    uint16_t* __restrict__ wcomb)
{
  const size_t n_qa4 = 6400064;            // 100001*256/4
  const size_t n_w4  = 32768;              // 512*256/4
  size_t stride = (size_t)gridDim.x*blockDim.x;
  for (size_t i = (size_t)blockIdx.x*256 + threadIdx.x; i < n_qa4 + n_w4; i += stride){
    float4 v;
    if (i < n_qa4){
      v = ((const float4*)qa_tab)[i];
      ushort4 o; o.x=f2b(v.x); o.y=f2b(v.y); o.z=f2b(v.z); o.w=f2b(v.w);
      ((ushort4*)qa_bf)[i] = o;
    } else {
      size_t j = i - n_qa4;
      size_t f = j*4;
      int col = (int)(f >> 8), k = (int)(f & 255);
      const float* srcp = (col < 256) ? (We + (size_t)col*256 + k)
                                      : (Wa + (size_t)(col-256)*256 + k);
      v = *(const float4*)srcp;
      ushort4 o; o.x=f2b(v.x); o.y=f2b(v.y); o.z=f2b(v.z); o.w=f2b(v.w);
      ((ushort4*)wcomb)[j] = o;
    }
  }
}

// =====================================================================
// K-cvt2 (after k_scan, into dead w_ws region): q_tab -> q_bf, Wr -> wr_bf
// =====================================================================
__global__ __launch_bounds__(256) void k_cvt2(
    const float* __restrict__ q_tab, const float* __restrict__ Wr,
    uint16_t* __restrict__ q_bf, uint16_t* __restrict__ wr_bf)
{
  const size_t n_q4  = 1600032;            // 50001*128/4
  const size_t n_wr4 = 12288;              // 128*384/4
  size_t stride = (size_t)gridDim.x*blockDim.x;
  for (size_t i = (size_t)blockIdx.x*256 + threadIdx.x; i < n_q4 + n_wr4; i += stride){
    if (i < n_q4){
      float4 v = ((const float4*)q_tab)[i];
      ushort4 o; o.x=f2b(v.x); o.y=f2b(v.y); o.z=f2b(v.z); o.w=f2b(v.w);
      ((ushort4*)q_bf)[i] = o;
    } else {
      size_t j = i - n_q4;
      float4 v = ((const float4*)Wr)[j];
      ushort4 o; o.x=f2b(v.x); o.y=f2b(v.y); o.z=f2b(v.z); o.w=f2b(v.w);
      ((ushort4*)wr_bf)[j] = o;
    }
  }
}

// =====================================================================
// K1b: ea via bf16 MFMA; staging via global_load_lds; XCD-sibling swizzle.
// Epilogue stores INTERLEAVED: ea_ws u16 index = row*512 + 2*col + isa.
// =====================================================================
__global__ __launch_bounds__(256, 2) void k_ea(
    const int* __restrict__ qa_data, const uint16_t* __restrict__ qa_bf,
    const uint16_t* __restrict__ wcomb, const float* __restrict__ be,
    const float* __restrict__ ba, uint16_t* __restrict__ ea16)
{
  __shared__ uint16_t Ab[128*32];
  __shared__ uint16_t Bb[128*32];
  const int tid = threadIdx.x;
  const int lane = tid & 63, wid = tid >> 6;
  const int braw = blockIdx.x;
  const int nb = (braw >> 3) & 3;
  const int mb = (braw & 7) | ((braw >> 5) << 3);
  const int rb = mb*128, cb = nb*128;

  const char* qac = (const char*)qa_bf;
  size_t aoff0, aoff1;
  {
    int r0 = wid*32 + (lane>>2);
    aoff0 = (size_t)qa_data[rb + r0]*512      + (size_t)(lane&3)*16;
    aoff1 = (size_t)qa_data[rb + r0 + 16]*512 + (size_t)(lane&3)*16;
  }
  const char* wcb = (const char*)wcomb;
  size_t boff0 = (size_t)(cb + wid*32 + (lane>>2))*512 + (size_t)(lane&3)*16;
  size_t boff1 = boff0 + 16*512;

  const int wr = (wid>>1)*64, wc = (wid&1)*64;
  float bias[4];
  #pragma unroll
  for (int tj=0;tj<4;tj++){
    int colg = cb + wc + tj*16 + (lane&15);
    bias[tj] = (nb<2) ? be[colg] : ba[colg-256];
  }

  f32x4 acc[4][4];
  #pragma unroll
  for (int i=0;i<4;i++){
    #pragma unroll
    for (int j=0;j<4;j++) acc[i][j] = (f32x4)(0.f);
  }

  #pragma unroll 1
  for (int kc=0; kc<8; kc++){
    __syncthreads();
    gl_lds16(qac + aoff0 + (size_t)kc*64, &Ab[(wid*2+0)*512]);
    gl_lds16(qac + aoff1 + (size_t)kc*64, &Ab[(wid*2+1)*512]);
    gl_lds16(wcb + boff0 + (size_t)kc*64, &Bb[(wid*2+0)*512]);
    gl_lds16(wcb + boff1 + (size_t)kc*64, &Bb[(wid*2+1)*512]);
    __syncthreads();
    bf16x8 af[4], bfr[4];
    #pragma unroll
    for (int ti=0;ti<4;ti++)
      af[ti] = *(const bf16x8*)&Ab[(wr + ti*16 + (lane&15))*32 + (lane>>4)*8];
    #pragma unroll
    for (int tj=0;tj<4;tj++)
      bfr[tj] = *(const bf16x8*)&Bb[(wc + tj*16 + (lane&15))*32 + (lane>>4)*8];
    #pragma unroll
    for (int ti=0;ti<4;ti++){
      #pragma unroll
      for (int tj=0;tj<4;tj++)
        acc[ti][tj] = __builtin_amdgcn_mfma_f32_16x16x32_bf16(af[ti], bfr[tj], acc[ti][tj], 0, 0, 0);
    }
  }
  const int rq = (lane>>4)*4, cl = lane&15;
  const int isa = (nb >= 2);
  const int cbase = (cb & 255) + wc;     // col within the 256-wide half
  #pragma unroll
  for (int ti=0;ti<4;ti++){
    #pragma unroll
    for (int r=0;r<4;r++){
      int row = rb + wr + ti*16 + rq + r;
      uint16_t* orow = ea16 + (size_t)row*512;
      #pragma unroll
      for (int tj=0;tj<4;tj++){
        float x = acc[ti][tj][r] + bias[tj];
        float v = (nb<2) ? (1.f/(1.f+__expf(-x)))
                         : (1.f - 2.f/(__expf(2.f*x)+1.f));
        orow[2*(cbase + tj*16 + cl) + isa] = f2b(v);
      }
    }
  }
}

// =====================================================================
// K2 v5: split-m scan with INTRA-WAVE exchange (zero per-step barriers).
// 256 blocks x 512 threads; d = tid>>1, h = tid&1 (partner = adjacent lane).
// h owns quads {2*qq+h}; quad 12 -> h0 only (h1's wv[6] zeroed via hm).
// Exchange: rd = rp + shfl_xor(rp,1). Barrier only per 10-step group (wbuf).
// e/a packed: one u32 load/step from interleaved ea16.
// =====================================================================
__global__ __launch_bounds__(512, 2) void k_scan(
    const int* __restrict__ q_data, const float* __restrict__ w_ws,
    const uint32_t* __restrict__ ea32, const float* __restrict__ Mv0,
    __hip_bfloat16* __restrict__ reads_ws)
{
  __shared__ float wbuf[2][GSZ*52];
  const int tid = threadIdx.x;
  const int d = tid >> 1, h = tid & 1;
  const int base = blockIdx.x*TLEN;
  const float hm = (h == 0) ? 1.f : 0.f;

  float Mv[28];
  #pragma unroll
  for (int qq=0; qq<7; qq++){
    int quad = 2*qq + h;
    #pragma unroll
    for (int e=0;e<4;e++){
      int m = quad*4 + e;
      Mv[qq*4+e] = (m < MSZ) ? Mv0[m*256 + d] : 0.f;
    }
  }

  float4 wreg;
  uint32_t eacur[GSZ], eanxt[GSZ];
  int qcur[GSZ], qnxt[GSZ];

  if (tid < 130) wreg = ((const float4*)(w_ws + (size_t)base*52))[tid];
  #pragma unroll
  for (int j=0;j<GSZ;j++){
    eacur[j] = ea32[(size_t)(base+j)*256 + d];
    qcur[j] = q_data[base+j];
  }
  if (tid < 130) ((float4*)wbuf[0])[tid] = wreg;
  __syncthreads();

  #pragma unroll 1
  for (int g=0; g<50; g++){
    if (g < 49){
      const int sn = base + (g+1)*GSZ;
      if (tid < 130) wreg = ((const float4*)(w_ws + (size_t)sn*52))[tid];
      #pragma unroll
      for (int j=0;j<GSZ;j++){
        eanxt[j] = ea32[(size_t)(sn+j)*256 + d];
        qnxt[j] = q_data[sn+j];
      }
    }
    const float* wb = wbuf[g&1];
    const int s0 = base + g*GSZ;
    #pragma unroll
    for (int j=0;j<GSZ;j++){
      const float4* wq = (const float4*)(wb + j*52);
      float ef = bflo32(eacur[j]), af = bfhi32(eacur[j]);
      float4 wv[7];
      #pragma unroll
      for (int qq=0; qq<6; qq++) wv[qq] = wq[2*qq + h];
      { float4 t = wq[12]; wv[6] = make_float4(t.x*hm, t.y*hm, t.z*hm, t.w*hm); }
      float r0=0.f, r1=0.f, r2=0.f, r3=0.f;
      #pragma unroll
      for (int qq=0; qq<7; qq++){
        r0 = fmaf(wv[qq].x, Mv[qq*4+0], r0);
        r1 = fmaf(wv[qq].y, Mv[qq*4+1], r1);
        r2 = fmaf(wv[qq].z, Mv[qq*4+2], r2);
        r3 = fmaf(wv[qq].w, Mv[qq*4+3], r3);
      }
      float rp = (r0+r1)+(r2+r3);
      float rd = rp + __shfl_xor(rp, 1);
      if (h == 0) reads_ws[(size_t)(s0+j)*256 + d] = __float2bfloat16(rd);
      if (qcur[j] > 0){   // block-uniform branch (q==0 is ~never)
        #pragma unroll
        for (int qq=0; qq<7; qq++){
          { float tt = fmaf(ef, Mv[qq*4+0], -af); Mv[qq*4+0] = fmaf(-wv[qq].x, tt, Mv[qq*4+0]); }
          { float tt = fmaf(ef, Mv[qq*4+1], -af); Mv[qq*4+1] = fmaf(-wv[qq].y, tt, Mv[qq*4+1]); }
          { float tt = fmaf(ef, Mv[qq*4+2], -af); Mv[qq*4+2] = fmaf(-wv[qq].z, tt, Mv[qq*4+2]); }
          { float tt = fmaf(ef, Mv[qq*4+3], -af); Mv[qq*4+3] = fmaf(-wv[qq].w, tt, Mv[qq*4+3]); }
        }
      }
    }
    if (g < 49){
      if (tid < 130) ((float4*)wbuf[(g+1)&1])[tid] = wreg;
      #pragma unroll
      for (int j=0;j<GSZ;j++){ eacur[j]=eanxt[j]; qcur[j]=qnxt[j]; }
    }
    __syncthreads();
  }
}

// =====================================================================
// K3 v4: bf16 MFMA, 128-row tiles (1000 blocks). Per wave: 32 rows x 128 cols,
// 16 MFMA per K-chunk (double R6's density per barrier).
// =====================================================================
__global__ __launch_bounds__(256, 2) void k_final(
    const int* __restrict__ q_data, const uint16_t* __restrict__ q_bf,
    const uint16_t* __restrict__ reads16, const uint16_t* __restrict__ wr_bf,
    const float* __restrict__ br, const float* __restrict__ Wp,
    const float* __restrict__ bp, const float* __restrict__ target,
    float* __restrict__ out, float* __restrict__ parts)
{
  __shared__ uint16_t Ab[128*32];   // 8 KB
  __shared__ uint16_t Bb[128*32];   // 8 KB
  __shared__ float redbuf[8];
  const int tid = threadIdx.x;
  const int lane = tid & 63, wid = tid >> 6;
  const int rb = blockIdx.x * 128;

  const char* rdc = (const char*)reads16;
  const char* qbc = (const char*)q_bf;
  const char* wrc = (const char*)wr_bf;
  const int ar0 = wid*32 + (lane>>2), ar1 = ar0 + 16;
  size_t aoffr0 = (size_t)(rb+ar0)*512 + (size_t)(lane&3)*16;
  size_t aoffr1 = (size_t)(rb+ar1)*512 + (size_t)(lane&3)*16;
  size_t aoffq0 = (size_t)q_data[rb+ar0]*256 + (size_t)(lane&3)*16;
  size_t aoffq1 = (size_t)q_data[rb+ar1]*256 + (size_t)(lane&3)*16;
  size_t boff0  = (size_t)(wid*32 + (lane>>2))*768 + (size_t)(lane&3)*16;
  size_t boff1  = boff0 + 16*768;

  f32x4 acc[2][8];
  #pragma unroll
  for (int ti=0;ti<2;ti++){
    #pragma unroll
    for (int tj=0;tj<8;tj++) acc[ti][tj] = (f32x4)(0.f);
  }

  #pragma unroll 1
  for (int kc=0; kc<12; kc++){
    __syncthreads();
    if (kc < 8){
      gl_lds16(rdc + aoffr0 + (size_t)kc*64, &Ab[(wid*2+0)*512]);
      gl_lds16(rdc + aoffr1 + (size_t)kc*64, &Ab[(wid*2+1)*512]);
    } else {
      gl_lds16(qbc + aoffq0 + (size_t)(kc-8)*64, &Ab[(wid*2+0)*512]);
      gl_lds16(qbc + aoffq1 + (size_t)(kc-8)*64, &Ab[(wid*2+1)*512]);
    }
    gl_lds16(wrc + boff0 + (size_t)kc*64, &Bb[(wid*2+0)*512]);
    gl_lds16(wrc + boff1 + (size_t)kc*64, &Bb[(wid*2+1)*512]);
    __syncthreads();
    bf16x8 af[2];
    #pragma unroll
    for (int ti=0;ti<2;ti++)
      af[ti] = *(const bf16x8*)&Ab[(wid*32 + ti*16 + (lane&15))*32 + (lane>>4)*8];
    #pragma unroll
    for (int tj=0;tj<8;tj++){
      bf16x8 bf = *(const bf16x8*)&Bb[(tj*16 + (lane&15))*32 + (lane>>4)*8];
      #pragma unroll
      for (int ti=0;ti<2;ti++)
        acc[ti][tj] = __builtin_amdgcn_mfma_f32_16x16x32_bf16(af[ti], bf, acc[ti][tj], 0, 0, 0);
    }
  }
  const int cl = lane & 15, rq = lane >> 4;
  float p[2][4] = {{0.f,0.f,0.f,0.f},{0.f,0.f,0.f,0.f}};
  #pragma unroll
  for (int tj=0;tj<8;tj++){
    int cg = tj*16 + cl;
    float brv = br[cg], wpv = Wp[cg];
    #pragma unroll
    for (int ti=0;ti<2;ti++){
      #pragma unroll
      for (int r=0;r<4;r++){
        float x = acc[ti][tj][r] + brv;
        float hh = 1.f - 2.f/(__expf(2.f*x)+1.f);
        p[ti][r] = fmaf(hh, wpv, p[ti][r]);
      }
    }
  }
  #pragma unroll
  for (int off=1; off<16; off<<=1){
    #pragma unroll
    for (int ti=0;ti<2;ti++){
      #pragma unroll
      for (int r=0;r<4;r++) p[ti][r] += __shfl_xor(p[ti][r], off);
    }
  }
  float bpv = bp[0];
  float lsum = 0.f, csum = 0.f;
  if (cl == 0){
    #pragma unroll
    for (int ti=0;ti<2;ti++){
      #pragma unroll
      for (int r=0;r<4;r++){
        int row = rb + wid*32 + ti*16 + rq*4 + r;
        float pred = p[ti][r] + bpv;
        out[1 + row] = 1.f/(1.f + __expf(-pred));
        float tg = target[row];
        if (tg >= 0.f){
          lsum += fmaxf(pred, 0.f) - pred*tg + log1pf(__expf(-fabsf(pred)));
          csum += 1.f;
        }
      }
    }
  }
  #pragma unroll
  for (int off=16; off<64; off<<=1){
    lsum += __shfl_xor(lsum, off);
    csum += __shfl_xor(csum, off);
  }
  if (lane == 0){ redbuf[wid*2] = lsum; redbuf[wid*2+1] = csum; }
  __syncthreads();
  if (tid == 0){
    parts[blockIdx.x]        = redbuf[0]+redbuf[2]+redbuf[4]+redbuf[6];
    parts[1000 + blockIdx.x] = redbuf[1]+redbuf[3]+redbuf[5]+redbuf[7];
  }
}

// =====================================================================
// K4: final loss reduction (1000 blocks' partials)
// =====================================================================
__global__ __launch_bounds__(256) void k_loss(
    const float* __restrict__ parts, float* __restrict__ out)
{
  __shared__ float red[8];
  const int tid = threadIdx.x;
  float l = 0.f, cn = 0.f;
  for (int i = tid; i < 1000; i += 256){ l += parts[i]; cn += parts[1000+i]; }
  #pragma unroll
  for (int off=32; off>0; off>>=1){ l += __shfl_xor(l, off); cn += __shfl_xor(cn, off); }
  if ((tid & 63) == 0){ red[(tid>>6)*2] = l; red[(tid>>6)*2+1] = cn; }
  __syncthreads();
  if (tid == 0){
    float L = red[0]+red[2]+red[4]+red[6];
    float C = red[1]+red[3]+red[5]+red[7];
    out[0] = L / fmaxf(C, 1.f);
  }
}

// =====================================================================
extern "C" void kernel_launch(void* const* d_in, const int* in_sizes, int n_in,
                              void* d_out, int out_size, void* d_ws, size_t ws_size,
                              hipStream_t stream) {
  const int*   q_data  = (const int*)d_in[0];
  const int*   qa_data = (const int*)d_in[1];
  const float* target  = (const float*)d_in[2];
  const float* q_tab   = (const float*)d_in[3];
  const float* qa_tab  = (const float*)d_in[4];
  const float* Mk  = (const float*)d_in[5];
  const float* Mv0 = (const float*)d_in[6];
  const float* We  = (const float*)d_in[7];
  const float* be  = (const float*)d_in[8];
  const float* Wa  = (const float*)d_in[9];
  const float* ba  = (const float*)d_in[10];
  const float* Wr  = (const float*)d_in[11];
  const float* br  = (const float*)d_in[12];
  const float* Wp  = (const float*)d_in[13];
  const float* bp  = (const float*)d_in[14];

  char* ws = (char*)d_ws;
  float*          w_ws     = (float*)ws;                           // [0, 26,624,000)
  uint16_t*       ea16     = (uint16_t*)(ws + 26624000);           // 131,072,000 B (interleaved e,a)
  uint16_t*       qa_bf    = (uint16_t*)(ws + 157696000);          // 51,200,512 B
  uint16_t*       wcomb    = (uint16_t*)(ws + 208896512);          // 262,144 B
  __hip_bfloat16* reads_ws = (__hip_bfloat16*)(ws + 157696000);    // 65,536,000 B (after k_ea)
  float*          parts    = (float*)ws;                           // 8,000 B (after k_scan)
  uint16_t*       q_bf     = (uint16_t*)(ws + 2000000);            // 12,800,256 B (after k_scan)
  uint16_t*       wr_bf    = (uint16_t*)(ws + 16000000);           // 98,304 B (after k_scan)

  float* out = (float*)d_out;   // f32: [loss, probs(128000)]

  k_w    <<<1000, 128, 0, stream>>>(q_data, q_tab, Mk, w_ws);
  k_cvt  <<<2048, 256, 0, stream>>>(qa_tab, We, Wa, qa_bf, wcomb);
  k_ea   <<<4000, 256, 0, stream>>>(qa_data, qa_bf, wcomb, be, ba, ea16);
  k_scan <<<256,  512, 0, stream>>>(q_data, w_ws, (const uint32_t*)ea16, Mv0, reads_ws);
  k_cvt2 <<<1024, 256, 0, stream>>>(q_tab, Wr, q_bf, wr_bf);
  k_final<<<1000, 256, 0, stream>>>(q_data, q_bf, (const uint16_t*)reads_ws, wr_bf, br, Wp, bp, target, out, parts);
  k_loss <<<1,    256, 0, stream>>>(parts, out);
}